// Round 5
// baseline (10055.028 us; speedup 1.0000x reference)
//
#include <hip/hip_runtime.h>

// ---------------------------------------------------------------------------
// MultiLayerNormGRU on MI355X (gfx950) — round 5.
// Phase structure as rounds 2-4 (x-precompute + weight-resident recurrence).
// Recurrent kernel: 8 waves; ALL weights (gates 128 + cand 64 regs) pinned in
// AGPRs via "+a" asm (zero-copy MFMA operands on gfx950's unified file);
// LDS only for h/rh tiles + LN stats (≈21 KB). 16 ds_read_b128/thread/step.
// ---------------------------------------------------------------------------

#define B_   512
#define T_   512
#define DIN  64
#define H_   256
#define OUT_ 64
#define EPS_ 1e-5f

typedef __attribute__((ext_vector_type(8))) short bf16x8;
typedef __attribute__((ext_vector_type(4))) float f32x4;

__device__ __forceinline__ unsigned short f2bf(float f) {
  unsigned int u = __float_as_uint(f);
  u += 0x7fffu + ((u >> 16) & 1u);          // RNE f32 -> bf16
  return (unsigned short)(u >> 16);
}
__device__ __forceinline__ float bfh(unsigned short u) {
  return __uint_as_float(((unsigned int)u) << 16);
}
__device__ __forceinline__ float sigm_(float x) {
  return __builtin_amdgcn_rcpf(1.f + __expf(-x));
}
__device__ __forceinline__ float tanh_(float x) {
  return 1.f - 2.f * __builtin_amdgcn_rcpf(__expf(2.f * x) + 1.f);
}
template<int C>
__device__ __forceinline__ float dpp_add(float v) {
  int r = __builtin_amdgcn_update_dpp(0, __float_as_int(v), C, 0xF, 0xF, false);
  return v + __int_as_float(r);
}
__device__ __forceinline__ float red16(float v) {  // sum over 16-lane row
  v = dpp_add<0x121>(v);
  v = dpp_add<0x122>(v);
  v = dpp_add<0x124>(v);
  v = dpp_add<0x128>(v);
  return v;
}

// Pin an 8-element bf16x8 array into AGPRs; the "+a" in-loop pin creates a
// loop-carried dependency so the compiler can neither rematerialize the loads
// nor copy through VGPRs (MFMA reads AGPR operands directly on gfx950).
#define PIN8A(a) asm volatile("" : "+a"(a[0]), "+a"(a[1]), "+a"(a[2]), "+a"(a[3]), \
                                   "+a"(a[4]), "+a"(a[5]), "+a"(a[6]), "+a"(a[7]))

// ------------------------- prep kernels --------------------------------------
__global__ void prep_frag(const float* __restrict__ w, unsigned short* __restrict__ dst,
                          int N, int Ksrc, int koff) {
  int gid = blockIdx.x * 256 + threadIdx.x;
  if (gid >= N * 256) return;
  int n = gid >> 8, k = gid & 255;
  int idx = (((n >> 4) * 8 + (k >> 5)) * 64 + ((n & 15) + 16 * ((k >> 3) & 3))) * 8 + (k & 7);
  dst[idx] = f2bf(w[(size_t)n * Ksrc + koff + k]);
}

__global__ void prep_wx(const float* __restrict__ wg, const float* __restrict__ wc,
                        unsigned short* __restrict__ dst, int KX, int Kg, int Kc) {
  int gid = blockIdx.x * 256 + threadIdx.x;
  if (gid >= 768 * KX) return;
  int n = gid / KX, k = gid - n * KX;
  float v = (n < 512) ? wg[(size_t)n * Kg + k] : wc[(size_t)(n - 512) * Kc + k];
  dst[gid] = f2bf(v);
}

__global__ void bias_cat(const float* __restrict__ bg, const float* __restrict__ bc,
                         float* __restrict__ dst) {
  int i = blockIdx.x * 256 + threadIdx.x;
  if (i < 768) dst[i] = (i < 512) ? bg[i] : bc[i - 512];
}

// ------------------------- precomp GEMM (phases A, C) ------------------------
template<int KX, bool AFP32>
__launch_bounds__(256)
__global__ void precomp(const void* __restrict__ Asrc,
                        const unsigned short* __restrict__ wx,
                        const float* __restrict__ bias,
                        unsigned short* __restrict__ Pc,
                        int TC, int t0)
{
  __shared__ __align__(16) unsigned short A_s[8 * 2 * 64 * 8];
  __shared__ __align__(16) unsigned short B_s[8 * 2 * 64 * 8];

  const int tid = threadIdx.x, lane = tid & 63, wv = tid >> 6;
  const int m0 = blockIdx.x * 128, nb = blockIdx.y * 128;
  const int bt = m0 / (TC * 16);
  const int tt0 = (m0 - bt * TC * 16) >> 4;
  const int mq = wv >> 1, nq = wv & 1;
  const int crow0 = (lane >> 4) * 4;

  f32x4 acc[4][4];
#pragma unroll
  for (int i = 0; i < 4; ++i)
#pragma unroll
    for (int j = 0; j < 4; ++j) acc[i][j] = (f32x4){0, 0, 0, 0};

  for (int kb = 0; kb < KX / 64; ++kb) {
    __syncthreads();
#pragma unroll
    for (int it = 0; it < 4; ++it) {
      int s = tid + it * 256;
      int rg = s >> 3, k8 = s & 7;
      int mt = rg >> 4, r15 = rg & 15;
      int dl = r15 + 16 * (k8 & 3), kc = k8 >> 2;
      if (AFP32) {
        const float* xp = (const float*)Asrc +
            (((size_t)(bt * 16 + r15)) * T_ + (t0 + tt0 + mt)) * DIN + kb * 64 + k8 * 8;
        float4 u0 = *(const float4*)xp, u1 = *(const float4*)(xp + 4);
        unsigned short tmp[8];
        tmp[0] = f2bf(u0.x); tmp[1] = f2bf(u0.y); tmp[2] = f2bf(u0.z); tmp[3] = f2bf(u0.w);
        tmp[4] = f2bf(u1.x); tmp[5] = f2bf(u1.y); tmp[6] = f2bf(u1.z); tmp[7] = f2bf(u1.w);
        *reinterpret_cast<bf16x8*>(&A_s[((mt * 2 + kc) * 64 + dl) * 8]) =
            *reinterpret_cast<bf16x8*>(tmp);
      } else {
        const unsigned short* ap = (const unsigned short*)Asrc +
            ((size_t)(m0 + rg)) * KX + kb * 64 + k8 * 8;
        *reinterpret_cast<bf16x8*>(&A_s[((mt * 2 + kc) * 64 + dl) * 8]) =
            *reinterpret_cast<const bf16x8*>(ap);
      }
      const unsigned short* bp = wx + ((size_t)(nb + rg)) * KX + kb * 64 + k8 * 8;
      *reinterpret_cast<bf16x8*>(&B_s[((mt * 2 + kc) * 64 + dl) * 8]) =
          *reinterpret_cast<const bf16x8*>(bp);
    }
    __syncthreads();
#pragma unroll
    for (int kc = 0; kc < 2; ++kc) {
      bf16x8 av[4], bv[4];
#pragma unroll
      for (int i = 0; i < 4; ++i) {
        av[i] = *reinterpret_cast<const bf16x8*>(&A_s[(((mq * 4 + i) * 2 + kc) * 64 + lane) * 8]);
        bv[i] = *reinterpret_cast<const bf16x8*>(&B_s[(((nq * 4 + i) * 2 + kc) * 64 + lane) * 8]);
      }
#pragma unroll
      for (int i = 0; i < 4; ++i)
#pragma unroll
        for (int j = 0; j < 4; ++j)
          acc[i][j] = __builtin_amdgcn_mfma_f32_16x16x32_bf16(av[i], bv[j], acc[i][j], 0, 0, 0);
    }
  }
  float bb[4];
#pragma unroll
  for (int j = 0; j < 4; ++j) bb[j] = bias[nb + nq * 64 + j * 16 + (lane & 15)];
#pragma unroll
  for (int i = 0; i < 4; ++i) {
    int tt = tt0 + mq * 4 + i;
#pragma unroll
    for (int j = 0; j < 4; ++j) {
      int n = nb + nq * 64 + j * 16 + (lane & 15);
      ushort4 o;
      o.x = f2bf(acc[i][j][0] + bb[j]); o.y = f2bf(acc[i][j][1] + bb[j]);
      o.z = f2bf(acc[i][j][2] + bb[j]); o.w = f2bf(acc[i][j][3] + bb[j]);
      *reinterpret_cast<ushort4*>(&Pc[((size_t)(bt * TC + tt) * 768 + n) * 16 + crow0]) = o;
    }
  }
}

// ------------------------- recurrent kernel (phases B, D) --------------------
// 8 waves; wave w owns gate ntiles {2w,2w+1,16+2w,17+2w} and cand ntiles
// {2w,2w+1}; all 6 ntile fragment arrays AGPR-pinned.
template<bool FIRST, bool L0>
__launch_bounds__(512, 2)
__global__ void gru_layer(
    const unsigned short* __restrict__ gfrag,
    const unsigned short* __restrict__ cfrag,
    const unsigned short* __restrict__ Pc,
    const float* __restrict__ gnw, const float* __restrict__ gnb,
    const float* __restrict__ cnw, const float* __restrict__ cnb,
    float* __restrict__ hstate,
    unsigned short* __restrict__ h0out,
    int TC)
{
  __shared__ __align__(16) unsigned short h_s[16][264];
  __shared__ __align__(16) unsigned short rh_s[16][264];
  __shared__ __align__(16) float sumP[8][20];
  __shared__ __align__(16) float sqP[8][20];
  __shared__ __align__(8) float2 mnrs[16];

  const int tid = threadIdx.x, lane = tid & 63, wv = tid >> 6;  // wv 0..7
  const int bt = blockIdx.x, b0 = bt * 16;
  const int arow = lane & 15, koff = (lane >> 4) * 8, crow0 = (lane >> 4) * 4;
  const int colr0 = 32 * wv + (lane & 15), colr1 = colr0 + 16;
  const int nt0 = 2 * wv, nt1 = 2 * wv + 1, nt2 = 16 + 2 * wv, nt3 = 17 + 2 * wv;

  // all weights -> registers (AGPR-pinned below): 6 x 32 = 192 regs
  bf16x8 wgr0[8], wgr1[8], wgr2[8], wgr3[8], wcr0[8], wcr1[8];
#pragma unroll
  for (int kc = 0; kc < 8; ++kc) {
    wgr0[kc] = *reinterpret_cast<const bf16x8*>(&gfrag[((nt0 * 8 + kc) * 64 + lane) * 8]);
    wgr1[kc] = *reinterpret_cast<const bf16x8*>(&gfrag[((nt1 * 8 + kc) * 64 + lane) * 8]);
    wgr2[kc] = *reinterpret_cast<const bf16x8*>(&gfrag[((nt2 * 8 + kc) * 64 + lane) * 8]);
    wgr3[kc] = *reinterpret_cast<const bf16x8*>(&gfrag[((nt3 * 8 + kc) * 64 + lane) * 8]);
    wcr0[kc] = *reinterpret_cast<const bf16x8*>(&cfrag[((nt0 * 8 + kc) * 64 + lane) * 8]);
    wcr1[kc] = *reinterpret_cast<const bf16x8*>(&cfrag[((nt1 * 8 + kc) * 64 + lane) * 8]);
  }

  const float gw_r0 = gnw[colr0], gb_r0 = gnb[colr0];
  const float gw_r1 = gnw[colr1], gb_r1 = gnb[colr1];
  const float gw_z0 = gnw[256 + colr0], gb_z0 = gnb[256 + colr0];
  const float gw_z1 = gnw[256 + colr1], gb_z1 = gnb[256 + colr1];
  const float cw0 = cnw[colr0], cb0 = cnb[colr0];
  const float cw1 = cnw[colr1], cb1 = cnb[colr1];

  float hm[2][4];
  if (FIRST) {
#pragma unroll
    for (int g = 0; g < 4; ++g) { hm[0][g] = 0.f; hm[1][g] = 0.f; }
    for (int i = tid; i < 16 * 264; i += 512) (&h_s[0][0])[i] = 0;
  } else {
#pragma unroll
    for (int g = 0; g < 4; ++g) {
      hm[0][g] = hstate[(size_t)(b0 + crow0 + g) * 256 + colr0];
      hm[1][g] = hstate[(size_t)(b0 + crow0 + g) * 256 + colr1];
    }
    int r = tid >> 5, c8 = (tid & 31) * 8;
    float4 v0 = *reinterpret_cast<const float4*>(&hstate[(size_t)(b0 + r) * 256 + c8]);
    float4 v1 = *reinterpret_cast<const float4*>(&hstate[(size_t)(b0 + r) * 256 + c8 + 4]);
    ushort4 o0, o1;
    o0.x = f2bf(v0.x); o0.y = f2bf(v0.y); o0.z = f2bf(v0.z); o0.w = f2bf(v0.w);
    o1.x = f2bf(v1.x); o1.y = f2bf(v1.y); o1.z = f2bf(v1.z); o1.w = f2bf(v1.w);
    *reinterpret_cast<ushort4*>(&h_s[r][c8]) = o0;
    *reinterpret_cast<ushort4*>(&h_s[r][c8 + 4]) = o1;
  }
  __syncthreads();

  const unsigned short* Pr0 = Pc + ((size_t)bt * TC * 768 + colr0) * 16;

  for (int tt = 0; tt < TC; ++tt) {
    // AGPR pins: loop-carried dep, no remat, no VGPR copies
    PIN8A(wgr0); PIN8A(wgr1); PIN8A(wgr2); PIN8A(wgr3); PIN8A(wcr0); PIN8A(wcr1);

    ushort4 pr0 = *reinterpret_cast<const ushort4*>(Pr0 + crow0);
    ushort4 pr1 = *reinterpret_cast<const ushort4*>(Pr0 + 16 * 16 + crow0);
    ushort4 pz0 = *reinterpret_cast<const ushort4*>(Pr0 + 256 * 16 + crow0);
    ushort4 pz1 = *reinterpret_cast<const ushort4*>(Pr0 + 272 * 16 + crow0);
    ushort4 pn0 = *reinterpret_cast<const ushort4*>(Pr0 + 512 * 16 + crow0);
    ushort4 pn1 = *reinterpret_cast<const ushort4*>(Pr0 + 528 * 16 + crow0);
    Pr0 += 12288;

    // ---- gates MFMA (AGPR weights) ----
    f32x4 a0 = {0, 0, 0, 0}, a1 = {0, 0, 0, 0}, a2 = {0, 0, 0, 0}, a3 = {0, 0, 0, 0};
#pragma unroll
    for (int kc = 0; kc < 8; ++kc) {
      bf16x8 av = *reinterpret_cast<const bf16x8*>(&h_s[arow][kc * 32 + koff]);
      a0 = __builtin_amdgcn_mfma_f32_16x16x32_bf16(av, wgr0[kc], a0, 0, 0, 0);
      a1 = __builtin_amdgcn_mfma_f32_16x16x32_bf16(av, wgr1[kc], a1, 0, 0, 0);
      a2 = __builtin_amdgcn_mfma_f32_16x16x32_bf16(av, wgr2[kc], a2, 0, 0, 0);
      a3 = __builtin_amdgcn_mfma_f32_16x16x32_bf16(av, wgr3[kc], a3, 0, 0, 0);
    }
    float vr0[4], vr1[4], vz0[4], vz1[4];
    {
      float s4[4], q4[4];
#pragma unroll
      for (int g = 0; g < 4; ++g) {
        vr0[g] = a0[g] + bfh(((const unsigned short*)&pr0)[g]);
        vr1[g] = a1[g] + bfh(((const unsigned short*)&pr1)[g]);
        vz0[g] = a2[g] + bfh(((const unsigned short*)&pz0)[g]);
        vz1[g] = a3[g] + bfh(((const unsigned short*)&pz1)[g]);
        s4[g] = red16(vr0[g] + vr1[g] + vz0[g] + vz1[g]);
        q4[g] = red16(vr0[g] * vr0[g] + vr1[g] * vr1[g] + vz0[g] * vz0[g] + vz1[g] * vz1[g]);
      }
      if ((lane & 15) == 0) {
        *reinterpret_cast<f32x4*>(&sumP[wv][crow0]) = (f32x4){s4[0], s4[1], s4[2], s4[3]};
        *reinterpret_cast<f32x4*>(&sqP[wv][crow0])  = (f32x4){q4[0], q4[1], q4[2], q4[3]};
      }
    }
    __syncthreads();                                   // B1

    // ---- gate LN stats + apply ----
    {
      int sg = lane >> 4, rr = lane & 15;
      float S = sumP[2 * sg][rr] + sumP[2 * sg + 1][rr];
      float Q = sqP[2 * sg][rr] + sqP[2 * sg + 1][rr];
      S += __shfl_xor(S, 16, 64); Q += __shfl_xor(Q, 16, 64);
      S += __shfl_xor(S, 32, 64); Q += __shfl_xor(Q, 32, 64);
      float mn = S * (1.f / 512.f);
      float rs = __builtin_amdgcn_rsqf(Q * (1.f / 512.f) - mn * mn + EPS_);
      if (lane < 16) mnrs[lane] = make_float2(mn, rs);
    }
    float zf[2][4];
#pragma unroll
    for (int g = 0; g < 4; ++g) {
      float2 mr = mnrs[crow0 + g];
      float rv0 = sigm_(fmaf((vr0[g] - mr.x) * mr.y, gw_r0, gb_r0));
      float rv1 = sigm_(fmaf((vr1[g] - mr.x) * mr.y, gw_r1, gb_r1));
      zf[0][g]  = sigm_(fmaf((vz0[g] - mr.x) * mr.y, gw_z0, gb_z0));
      zf[1][g]  = sigm_(fmaf((vz1[g] - mr.x) * mr.y, gw_z1, gb_z1));
      rh_s[crow0 + g][colr0] = f2bf(rv0 * hm[0][g]);
      rh_s[crow0 + g][colr1] = f2bf(rv1 * hm[1][g]);
    }
    __syncthreads();                                   // B2

    // ---- cand MFMA (AGPR weights) ----
    f32x4 c0 = {0, 0, 0, 0}, c1 = {0, 0, 0, 0};
#pragma unroll
    for (int kc = 0; kc < 8; ++kc) {
      bf16x8 av = *reinterpret_cast<const bf16x8*>(&rh_s[arow][kc * 32 + koff]);
      c0 = __builtin_amdgcn_mfma_f32_16x16x32_bf16(av, wcr0[kc], c0, 0, 0, 0);
      c1 = __builtin_amdgcn_mfma_f32_16x16x32_bf16(av, wcr1[kc], c1, 0, 0, 0);
    }
    float vc0[4], vc1[4];
    {
      float s4[4], q4[4];
#pragma unroll
      for (int g = 0; g < 4; ++g) {
        vc0[g] = c0[g] + bfh(((const unsigned short*)&pn0)[g]);
        vc1[g] = c1[g] + bfh(((const unsigned short*)&pn1)[g]);
        s4[g] = red16(vc0[g] + vc1[g]);
        q4[g] = red16(vc0[g] * vc0[g] + vc1[g] * vc1[g]);
      }
      if ((lane & 15) == 0) {
        *reinterpret_cast<f32x4*>(&sumP[wv][crow0]) = (f32x4){s4[0], s4[1], s4[2], s4[3]};
        *reinterpret_cast<f32x4*>(&sqP[wv][crow0])  = (f32x4){q4[0], q4[1], q4[2], q4[3]};
      }
    }
    __syncthreads();                                   // B3

    // ---- cand LN + tanh + h update ----
    {
      int sg = lane >> 4, rr = lane & 15;
      float S = sumP[2 * sg][rr] + sumP[2 * sg + 1][rr];
      float Q = sqP[2 * sg][rr] + sqP[2 * sg + 1][rr];
      S += __shfl_xor(S, 16, 64); Q += __shfl_xor(Q, 16, 64);
      S += __shfl_xor(S, 32, 64); Q += __shfl_xor(Q, 32, 64);
      float mn = S * (1.f / 256.f);
      float rs = __builtin_amdgcn_rsqf(Q * (1.f / 256.f) - mn * mn + EPS_);
      if (lane < 16) mnrs[lane] = make_float2(mn, rs);
    }
    unsigned short* hrow = L0 ? (h0out + (size_t)(bt * TC + tt) * 4096) : (unsigned short*)nullptr;
#pragma unroll
    for (int g = 0; g < 4; ++g) {
      float2 mr = mnrs[crow0 + g];
      float n0 = tanh_(fmaf((vc0[g] - mr.x) * mr.y, cw0, cb0));
      float n1 = tanh_(fmaf((vc1[g] - mr.x) * mr.y, cw1, cb1));
      float h0n = fmaf(zf[0][g], n0 - hm[0][g], hm[0][g]);
      float h1n = fmaf(zf[1][g], n1 - hm[1][g], hm[1][g]);
      hm[0][g] = h0n; hm[1][g] = h1n;
      unsigned short hb0 = f2bf(h0n), hb1 = f2bf(h1n);
      h_s[crow0 + g][colr0] = hb0;
      h_s[crow0 + g][colr1] = hb1;
      if (L0) {
        hrow[(size_t)(crow0 + g) * 256 + colr0] = hb0;
        hrow[(size_t)(crow0 + g) * 256 + colr1] = hb1;
      }
    }
    __syncthreads();                                   // B4
  }

#pragma unroll
  for (int g = 0; g < 4; ++g) {
    hstate[(size_t)(b0 + crow0 + g) * 256 + colr0] = hm[0][g];
    hstate[(size_t)(b0 + crow0 + g) * 256 + colr1] = hm[1][g];
  }
}

// ------------------------------- FC head -------------------------------------
__launch_bounds__(256)
__global__ void head_k(const float* __restrict__ h1, const float* __restrict__ fcW,
                       const float* __restrict__ fcb, float* __restrict__ out) {
  __shared__ float hs[16][256];
  const int tid = threadIdx.x, b0 = blockIdx.x * 16;
  for (int i = tid; i < 16 * 64; i += 256) {
    int r = i >> 6, c4 = (i & 63) * 4;
    *reinterpret_cast<float4*>(&hs[r][c4]) =
        *reinterpret_cast<const float4*>(&h1[(size_t)(b0 + r) * 256 + c4]);
  }
  __syncthreads();
  int r = tid >> 4, o = (tid & 15) * 4;
  float a0 = fcb[o], a1 = fcb[o + 1], a2 = fcb[o + 2], a3 = fcb[o + 3];
  for (int k = 0; k < 256; ++k) {
    float h = hs[r][k];
    a0 = fmaf(h, fcW[(size_t)(o + 0) * 256 + k], a0);
    a1 = fmaf(h, fcW[(size_t)(o + 1) * 256 + k], a1);
    a2 = fmaf(h, fcW[(size_t)(o + 2) * 256 + k], a2);
    a3 = fmaf(h, fcW[(size_t)(o + 3) * 256 + k], a3);
  }
  float4 ov = {a0, a1, a2, a3};
  *reinterpret_cast<float4*>(&out[(size_t)(b0 + r) * 64 + o]) = ov;
}

// --------------------------------- host --------------------------------------
extern "C" void kernel_launch(void* const* d_in, const int* in_sizes, int n_in,
                              void* d_out, int out_size, void* d_ws, size_t ws_size,
                              hipStream_t stream) {
  (void)in_sizes; (void)n_in; (void)out_size;
  const float* x    = (const float*)d_in[0];
  const float* Wg0  = (const float*)d_in[1];
  const float* bg0  = (const float*)d_in[2];
  const float* gnw0 = (const float*)d_in[3];
  const float* gnb0 = (const float*)d_in[4];
  const float* Wc0  = (const float*)d_in[5];
  const float* bc0  = (const float*)d_in[6];
  const float* cnw0 = (const float*)d_in[7];
  const float* cnb0 = (const float*)d_in[8];
  const float* Wg1  = (const float*)d_in[9];
  const float* bg1  = (const float*)d_in[10];
  const float* gnw1 = (const float*)d_in[11];
  const float* gnb1 = (const float*)d_in[12];
  const float* Wc1  = (const float*)d_in[13];
  const float* bc1  = (const float*)d_in[14];
  const float* cnw1 = (const float*)d_in[15];
  const float* cnb1 = (const float*)d_in[16];
  const float* fcW  = (const float*)d_in[17];
  const float* fcb  = (const float*)d_in[18];

  float* hst0 = (float*)d_ws;                 // 512*256
  float* hst1 = hst0 + 131072;
  float* b768_0 = hst1 + 131072;
  float* b768_1 = b768_0 + 768;
  unsigned short* g0h = (unsigned short*)(b768_1 + 768);
  unsigned short* c0h = g0h + 131072;
  unsigned short* g1h = c0h + 65536;
  unsigned short* c1h = g1h + 131072;
  unsigned short* wx0 = c1h + 65536;
  unsigned short* wx1 = wx0 + 49152;
  unsigned short* dynbase = wx1 + 196608;

  const size_t fixed_bytes = (size_t)((char*)dynbase - (char*)d_ws);
  int TC = 128;
  while (TC > 8) {
    size_t need = fixed_bytes + (size_t)TC * (262144 + 2 * 786432);
    if (need <= ws_size) break;
    TC >>= 1;
  }
  const int NC = T_ / TC;

  unsigned short* P0c = dynbase;
  unsigned short* P1c = P0c + (size_t)TC * 393216;
  unsigned short* h0c = P1c + (size_t)TC * 393216;

  prep_frag<<<512, 256, 0, stream>>>(Wg0, g0h, 512, 320, 64);
  prep_frag<<<256, 256, 0, stream>>>(Wc0, c0h, 256, 320, 64);
  prep_frag<<<512, 256, 0, stream>>>(Wg1, g1h, 512, 512, 256);
  prep_frag<<<256, 256, 0, stream>>>(Wc1, c1h, 256, 512, 256);
  prep_wx<<<192, 256, 0, stream>>>(Wg0, Wc0, wx0, 64, 320, 320);
  prep_wx<<<768, 256, 0, stream>>>(Wg1, Wc1, wx1, 256, 512, 512);
  bias_cat<<<3, 256, 0, stream>>>(bg0, bc0, b768_0);
  bias_cat<<<3, 256, 0, stream>>>(bg1, bc1, b768_1);

  dim3 pgrid(4 * TC, 6);
  for (int c = 0; c < NC; ++c) {
    precomp<64, true><<<pgrid, 256, 0, stream>>>(x, wx0, b768_0, P0c, TC, c * TC);
    if (c == 0)
      gru_layer<true, true><<<32, 512, 0, stream>>>(g0h, c0h, P0c,
          gnw0, gnb0, cnw0, cnb0, hst0, h0c, TC);
    else
      gru_layer<false, true><<<32, 512, 0, stream>>>(g0h, c0h, P0c,
          gnw0, gnb0, cnw0, cnb0, hst0, h0c, TC);
    precomp<256, false><<<pgrid, 256, 0, stream>>>(h0c, wx1, b768_1, P1c, TC, 0);
    if (c == 0)
      gru_layer<true, false><<<32, 512, 0, stream>>>(g1h, c1h, P1c,
          gnw1, gnb1, cnw1, cnb1, hst1, (unsigned short*)nullptr, TC);
    else
      gru_layer<false, false><<<32, 512, 0, stream>>>(g1h, c1h, P1c,
          gnw1, gnb1, cnw1, cnb1, hst1, (unsigned short*)nullptr, TC);
  }
  head_k<<<32, 256, 0, stream>>>(hst1, fcW, fcb, (float*)d_out);
}

// Round 6
// 2732.088 us; speedup vs baseline: 3.6803x; 3.6803x over previous
//
#include <hip/hip_runtime.h>

// ---------------------------------------------------------------------------
// MultiLayerNormGRU on MI355X (gfx950) — round 6.
// R4 inner kernel (best: 480 µs/dispatch) with two changes:
//  1) chunk-level software pipelining: fused 64-block kernel runs layer-1
//     chunk c alongside layer-0 chunk c+1 (independent work, 2x CUs busy).
//  2) gate weights pinned in AGPRs via "+a" (128 AGPR + ~100 VGPR < 256 cap;
//     R5's 192-reg pin overflowed and spilled). Cand weights stay in LDS.
// ---------------------------------------------------------------------------

#define B_   512
#define T_   512
#define DIN  64
#define H_   256
#define OUT_ 64
#define EPS_ 1e-5f

typedef __attribute__((ext_vector_type(8))) short bf16x8;
typedef __attribute__((ext_vector_type(4))) float f32x4;

__device__ __forceinline__ unsigned short f2bf(float f) {
  unsigned int u = __float_as_uint(f);
  u += 0x7fffu + ((u >> 16) & 1u);          // RNE f32 -> bf16
  return (unsigned short)(u >> 16);
}
__device__ __forceinline__ float bfh(unsigned short u) {
  return __uint_as_float(((unsigned int)u) << 16);
}
__device__ __forceinline__ float sigm_(float x) {
  return __builtin_amdgcn_rcpf(1.f + __expf(-x));
}
__device__ __forceinline__ float tanh_(float x) {
  return 1.f - 2.f * __builtin_amdgcn_rcpf(__expf(2.f * x) + 1.f);
}
template<int C>
__device__ __forceinline__ float dpp_add(float v) {
  int r = __builtin_amdgcn_update_dpp(0, __float_as_int(v), C, 0xF, 0xF, false);
  return v + __int_as_float(r);
}
__device__ __forceinline__ float red16(float v) {  // sum over 16-lane row
  v = dpp_add<0x121>(v);
  v = dpp_add<0x122>(v);
  v = dpp_add<0x124>(v);
  v = dpp_add<0x128>(v);
  return v;
}

// Pin an 8-element bf16x8 array into AGPRs (gates only: 128 AGPR total).
#define PIN8A(a) asm volatile("" : "+a"(a[0]), "+a"(a[1]), "+a"(a[2]), "+a"(a[3]), \
                                   "+a"(a[4]), "+a"(a[5]), "+a"(a[6]), "+a"(a[7]))

// ------------------------- prep kernels --------------------------------------
__global__ void prep_frag(const float* __restrict__ w, unsigned short* __restrict__ dst,
                          int N, int Ksrc, int koff) {
  int gid = blockIdx.x * 256 + threadIdx.x;
  if (gid >= N * 256) return;
  int n = gid >> 8, k = gid & 255;
  int idx = (((n >> 4) * 8 + (k >> 5)) * 64 + ((n & 15) + 16 * ((k >> 3) & 3))) * 8 + (k & 7);
  dst[idx] = f2bf(w[(size_t)n * Ksrc + koff + k]);
}

__global__ void prep_wx(const float* __restrict__ wg, const float* __restrict__ wc,
                        unsigned short* __restrict__ dst, int KX, int Kg, int Kc) {
  int gid = blockIdx.x * 256 + threadIdx.x;
  if (gid >= 768 * KX) return;
  int n = gid / KX, k = gid - n * KX;
  float v = (n < 512) ? wg[(size_t)n * Kg + k] : wc[(size_t)(n - 512) * Kc + k];
  dst[gid] = f2bf(v);
}

__global__ void bias_cat(const float* __restrict__ bg, const float* __restrict__ bc,
                         float* __restrict__ dst) {
  int i = blockIdx.x * 256 + threadIdx.x;
  if (i < 768) dst[i] = (i < 512) ? bg[i] : bc[i - 512];
}

// ------------------------- precomp GEMM (phases A, C) ------------------------
template<int KX, bool AFP32>
__launch_bounds__(256)
__global__ void precomp(const void* __restrict__ Asrc,
                        const unsigned short* __restrict__ wx,
                        const float* __restrict__ bias,
                        unsigned short* __restrict__ Pc,
                        int TC, int t0)
{
  __shared__ __align__(16) unsigned short A_s[8 * 2 * 64 * 8];
  __shared__ __align__(16) unsigned short B_s[8 * 2 * 64 * 8];

  const int tid = threadIdx.x, lane = tid & 63, wv = tid >> 6;
  const int m0 = blockIdx.x * 128, nb = blockIdx.y * 128;
  const int bt = m0 / (TC * 16);
  const int tt0 = (m0 - bt * TC * 16) >> 4;
  const int mq = wv >> 1, nq = wv & 1;
  const int crow0 = (lane >> 4) * 4;

  f32x4 acc[4][4];
#pragma unroll
  for (int i = 0; i < 4; ++i)
#pragma unroll
    for (int j = 0; j < 4; ++j) acc[i][j] = (f32x4){0, 0, 0, 0};

  for (int kb = 0; kb < KX / 64; ++kb) {
    __syncthreads();
#pragma unroll
    for (int it = 0; it < 4; ++it) {
      int s = tid + it * 256;
      int rg = s >> 3, k8 = s & 7;
      int mt = rg >> 4, r15 = rg & 15;
      int dl = r15 + 16 * (k8 & 3), kc = k8 >> 2;
      if (AFP32) {
        const float* xp = (const float*)Asrc +
            (((size_t)(bt * 16 + r15)) * T_ + (t0 + tt0 + mt)) * DIN + kb * 64 + k8 * 8;
        float4 u0 = *(const float4*)xp, u1 = *(const float4*)(xp + 4);
        unsigned short tmp[8];
        tmp[0] = f2bf(u0.x); tmp[1] = f2bf(u0.y); tmp[2] = f2bf(u0.z); tmp[3] = f2bf(u0.w);
        tmp[4] = f2bf(u1.x); tmp[5] = f2bf(u1.y); tmp[6] = f2bf(u1.z); tmp[7] = f2bf(u1.w);
        *reinterpret_cast<bf16x8*>(&A_s[((mt * 2 + kc) * 64 + dl) * 8]) =
            *reinterpret_cast<bf16x8*>(tmp);
      } else {
        const unsigned short* ap = (const unsigned short*)Asrc +
            ((size_t)(m0 + rg)) * KX + kb * 64 + k8 * 8;
        *reinterpret_cast<bf16x8*>(&A_s[((mt * 2 + kc) * 64 + dl) * 8]) =
            *reinterpret_cast<const bf16x8*>(ap);
      }
      const unsigned short* bp = wx + ((size_t)(nb + rg)) * KX + kb * 64 + k8 * 8;
      *reinterpret_cast<bf16x8*>(&B_s[((mt * 2 + kc) * 64 + dl) * 8]) =
          *reinterpret_cast<const bf16x8*>(bp);
    }
    __syncthreads();
#pragma unroll
    for (int kc = 0; kc < 2; ++kc) {
      bf16x8 av[4], bv[4];
#pragma unroll
      for (int i = 0; i < 4; ++i) {
        av[i] = *reinterpret_cast<const bf16x8*>(&A_s[(((mq * 4 + i) * 2 + kc) * 64 + lane) * 8]);
        bv[i] = *reinterpret_cast<const bf16x8*>(&B_s[(((nq * 4 + i) * 2 + kc) * 64 + lane) * 8]);
      }
#pragma unroll
      for (int i = 0; i < 4; ++i)
#pragma unroll
        for (int j = 0; j < 4; ++j)
          acc[i][j] = __builtin_amdgcn_mfma_f32_16x16x32_bf16(av[i], bv[j], acc[i][j], 0, 0, 0);
    }
  }
  float bb[4];
#pragma unroll
  for (int j = 0; j < 4; ++j) bb[j] = bias[nb + nq * 64 + j * 16 + (lane & 15)];
#pragma unroll
  for (int i = 0; i < 4; ++i) {
    int tt = tt0 + mq * 4 + i;
#pragma unroll
    for (int j = 0; j < 4; ++j) {
      int n = nb + nq * 64 + j * 16 + (lane & 15);
      ushort4 o;
      o.x = f2bf(acc[i][j][0] + bb[j]); o.y = f2bf(acc[i][j][1] + bb[j]);
      o.z = f2bf(acc[i][j][2] + bb[j]); o.w = f2bf(acc[i][j][3] + bb[j]);
      *reinterpret_cast<ushort4*>(&Pc[((size_t)(bt * TC + tt) * 768 + n) * 16 + crow0]) = o;
    }
  }
}

// ------------------------- fused recurrent kernel ----------------------------
// Blocks 0-31: layer-0 role (chunk cB), blocks 32-63: layer-1 role (chunk cD).
// Roles are data-independent (pipelined chunks), same code path.
__launch_bounds__(512, 2)
__global__ void gru_fused(
    // layer-0 role
    const unsigned short* __restrict__ g0, const unsigned short* __restrict__ c0,
    const unsigned short* __restrict__ P0,
    const float* __restrict__ gnw0, const float* __restrict__ gnb0,
    const float* __restrict__ cnw0, const float* __restrict__ cnb0,
    float* __restrict__ hst0, unsigned short* __restrict__ h0out,
    // layer-1 role
    const unsigned short* __restrict__ g1, const unsigned short* __restrict__ c1,
    const unsigned short* __restrict__ P1,
    const float* __restrict__ gnw1, const float* __restrict__ gnb1,
    const float* __restrict__ cnw1, const float* __restrict__ cnb1,
    float* __restrict__ hst1,
    int bActive, int dActive, int bFirst, int dFirst, int TC)
{
  __shared__ __align__(16) unsigned short wc_s[16 * 8 * 64 * 8];  // 128 KB cand
  __shared__ __align__(16) unsigned short h_s[16][264];
  __shared__ __align__(16) unsigned short rh_s[16][264];
  __shared__ __align__(16) float sumP[8][20];
  __shared__ __align__(16) float sqP[8][20];
  __shared__ __align__(8) float2 mnrs[16];

  const bool isB = ((int)blockIdx.x) < 32;
  if (isB ? !bActive : !dActive) return;

  const unsigned short* gfrag = isB ? g0 : g1;
  const unsigned short* cfrag = isB ? c0 : c1;
  const unsigned short* Pc    = isB ? P0 : P1;
  const float* gnw = isB ? gnw0 : gnw1;
  const float* gnb = isB ? gnb0 : gnb1;
  const float* cnw = isB ? cnw0 : cnw1;
  const float* cnb = isB ? cnb0 : cnb1;
  float* hstate = isB ? hst0 : hst1;
  unsigned short* h0o = isB ? h0out : (unsigned short*)nullptr;
  const int first = isB ? bFirst : dFirst;
  const int bt = isB ? blockIdx.x : (blockIdx.x - 32);

  const int tid = threadIdx.x, lane = tid & 63, wv = tid >> 6;  // wv 0..7
  const int b0 = bt * 16;
  const int arow = lane & 15, koff = (lane >> 4) * 8, crow0 = (lane >> 4) * 4;
  const int colr0 = 32 * wv + (lane & 15), colr1 = colr0 + 16;
  const int nt0 = 2 * wv, nt1 = 2 * wv + 1, nt2 = 16 + 2 * wv, nt3 = 17 + 2 * wv;

  // cand weights -> LDS (one-time)
  for (int i = tid; i < 8192; i += 512)
    *reinterpret_cast<bf16x8*>(&wc_s[i * 8]) = *reinterpret_cast<const bf16x8*>(&cfrag[i * 8]);

  // gate weights -> AGPR (4 ntiles x 8 kc = 128 regs), pinned each iteration
  bf16x8 wgr0[8], wgr1[8], wgr2[8], wgr3[8];
#pragma unroll
  for (int kc = 0; kc < 8; ++kc) {
    wgr0[kc] = *reinterpret_cast<const bf16x8*>(&gfrag[((nt0 * 8 + kc) * 64 + lane) * 8]);
    wgr1[kc] = *reinterpret_cast<const bf16x8*>(&gfrag[((nt1 * 8 + kc) * 64 + lane) * 8]);
    wgr2[kc] = *reinterpret_cast<const bf16x8*>(&gfrag[((nt2 * 8 + kc) * 64 + lane) * 8]);
    wgr3[kc] = *reinterpret_cast<const bf16x8*>(&gfrag[((nt3 * 8 + kc) * 64 + lane) * 8]);
  }

  const float gw_r0 = gnw[colr0], gb_r0 = gnb[colr0];
  const float gw_r1 = gnw[colr1], gb_r1 = gnb[colr1];
  const float gw_z0 = gnw[256 + colr0], gb_z0 = gnb[256 + colr0];
  const float gw_z1 = gnw[256 + colr1], gb_z1 = gnb[256 + colr1];
  const float cw0 = cnw[colr0], cb0 = cnb[colr0];
  const float cw1 = cnw[colr1], cb1 = cnb[colr1];

  float hm[2][4];
  if (first) {
#pragma unroll
    for (int g = 0; g < 4; ++g) { hm[0][g] = 0.f; hm[1][g] = 0.f; }
    for (int i = tid; i < 16 * 264; i += 512) (&h_s[0][0])[i] = 0;
  } else {
#pragma unroll
    for (int g = 0; g < 4; ++g) {
      hm[0][g] = hstate[(size_t)(b0 + crow0 + g) * 256 + colr0];
      hm[1][g] = hstate[(size_t)(b0 + crow0 + g) * 256 + colr1];
    }
    int r = tid >> 5, c8 = (tid & 31) * 8;
    float4 v0 = *reinterpret_cast<const float4*>(&hstate[(size_t)(b0 + r) * 256 + c8]);
    float4 v1 = *reinterpret_cast<const float4*>(&hstate[(size_t)(b0 + r) * 256 + c8 + 4]);
    ushort4 o0, o1;
    o0.x = f2bf(v0.x); o0.y = f2bf(v0.y); o0.z = f2bf(v0.z); o0.w = f2bf(v0.w);
    o1.x = f2bf(v1.x); o1.y = f2bf(v1.y); o1.z = f2bf(v1.z); o1.w = f2bf(v1.w);
    *reinterpret_cast<ushort4*>(&h_s[r][c8]) = o0;
    *reinterpret_cast<ushort4*>(&h_s[r][c8 + 4]) = o1;
  }
  __syncthreads();

  const unsigned short* Pr0 = Pc + ((size_t)bt * TC * 768 + colr0) * 16;

  for (int tt = 0; tt < TC; ++tt) {
    PIN8A(wgr0); PIN8A(wgr1); PIN8A(wgr2); PIN8A(wgr3);

    ushort4 pr0 = *reinterpret_cast<const ushort4*>(Pr0 + crow0);
    ushort4 pr1 = *reinterpret_cast<const ushort4*>(Pr0 + 16 * 16 + crow0);
    ushort4 pz0 = *reinterpret_cast<const ushort4*>(Pr0 + 256 * 16 + crow0);
    ushort4 pz1 = *reinterpret_cast<const ushort4*>(Pr0 + 272 * 16 + crow0);
    ushort4 pn0 = *reinterpret_cast<const ushort4*>(Pr0 + 512 * 16 + crow0);
    ushort4 pn1 = *reinterpret_cast<const ushort4*>(Pr0 + 528 * 16 + crow0);
    Pr0 += 12288;

    // ---- gates MFMA (AGPR weights) ----
    f32x4 a0 = {0, 0, 0, 0}, a1 = {0, 0, 0, 0}, a2 = {0, 0, 0, 0}, a3 = {0, 0, 0, 0};
#pragma unroll
    for (int kc = 0; kc < 8; ++kc) {
      bf16x8 av = *reinterpret_cast<const bf16x8*>(&h_s[arow][kc * 32 + koff]);
      a0 = __builtin_amdgcn_mfma_f32_16x16x32_bf16(av, wgr0[kc], a0, 0, 0, 0);
      a1 = __builtin_amdgcn_mfma_f32_16x16x32_bf16(av, wgr1[kc], a1, 0, 0, 0);
      a2 = __builtin_amdgcn_mfma_f32_16x16x32_bf16(av, wgr2[kc], a2, 0, 0, 0);
      a3 = __builtin_amdgcn_mfma_f32_16x16x32_bf16(av, wgr3[kc], a3, 0, 0, 0);
    }
    float vr0[4], vr1[4], vz0[4], vz1[4];
    {
      float s4[4], q4[4];
#pragma unroll
      for (int g = 0; g < 4; ++g) {
        vr0[g] = a0[g] + bfh(((const unsigned short*)&pr0)[g]);
        vr1[g] = a1[g] + bfh(((const unsigned short*)&pr1)[g]);
        vz0[g] = a2[g] + bfh(((const unsigned short*)&pz0)[g]);
        vz1[g] = a3[g] + bfh(((const unsigned short*)&pz1)[g]);
        s4[g] = red16(vr0[g] + vr1[g] + vz0[g] + vz1[g]);
        q4[g] = red16(vr0[g] * vr0[g] + vr1[g] * vr1[g] + vz0[g] * vz0[g] + vz1[g] * vz1[g]);
      }
      if ((lane & 15) == 0) {
        *reinterpret_cast<f32x4*>(&sumP[wv][crow0]) = (f32x4){s4[0], s4[1], s4[2], s4[3]};
        *reinterpret_cast<f32x4*>(&sqP[wv][crow0])  = (f32x4){q4[0], q4[1], q4[2], q4[3]};
      }
    }
    __syncthreads();                                   // B1

    // ---- gate LN stats + apply ----
    {
      int sg = lane >> 4, rr = lane & 15;
      float S = sumP[2 * sg][rr] + sumP[2 * sg + 1][rr];
      float Q = sqP[2 * sg][rr] + sqP[2 * sg + 1][rr];
      S += __shfl_xor(S, 16, 64); Q += __shfl_xor(Q, 16, 64);
      S += __shfl_xor(S, 32, 64); Q += __shfl_xor(Q, 32, 64);
      float mn = S * (1.f / 512.f);
      float rs = __builtin_amdgcn_rsqf(Q * (1.f / 512.f) - mn * mn + EPS_);
      if (lane < 16) mnrs[lane] = make_float2(mn, rs);
    }
    float zf[2][4];
#pragma unroll
    for (int g = 0; g < 4; ++g) {
      float2 mr = mnrs[crow0 + g];
      float rv0 = sigm_(fmaf((vr0[g] - mr.x) * mr.y, gw_r0, gb_r0));
      float rv1 = sigm_(fmaf((vr1[g] - mr.x) * mr.y, gw_r1, gb_r1));
      zf[0][g]  = sigm_(fmaf((vz0[g] - mr.x) * mr.y, gw_z0, gb_z0));
      zf[1][g]  = sigm_(fmaf((vz1[g] - mr.x) * mr.y, gw_z1, gb_z1));
      rh_s[crow0 + g][colr0] = f2bf(rv0 * hm[0][g]);
      rh_s[crow0 + g][colr1] = f2bf(rv1 * hm[1][g]);
    }
    __syncthreads();                                   // B2

    // ---- cand MFMA (LDS weights) ----
    f32x4 c0a = {0, 0, 0, 0}, c1a = {0, 0, 0, 0};
#pragma unroll
    for (int kc = 0; kc < 8; ++kc) {
      bf16x8 av = *reinterpret_cast<const bf16x8*>(&rh_s[arow][kc * 32 + koff]);
      bf16x8 b0v = *reinterpret_cast<const bf16x8*>(&wc_s[((nt0 * 8 + kc) * 64 + lane) * 8]);
      bf16x8 b1v = *reinterpret_cast<const bf16x8*>(&wc_s[((nt1 * 8 + kc) * 64 + lane) * 8]);
      c0a = __builtin_amdgcn_mfma_f32_16x16x32_bf16(av, b0v, c0a, 0, 0, 0);
      c1a = __builtin_amdgcn_mfma_f32_16x16x32_bf16(av, b1v, c1a, 0, 0, 0);
    }
    float vc0[4], vc1[4];
    {
      float s4[4], q4[4];
#pragma unroll
      for (int g = 0; g < 4; ++g) {
        vc0[g] = c0a[g] + bfh(((const unsigned short*)&pn0)[g]);
        vc1[g] = c1a[g] + bfh(((const unsigned short*)&pn1)[g]);
        s4[g] = red16(vc0[g] + vc1[g]);
        q4[g] = red16(vc0[g] * vc0[g] + vc1[g] * vc1[g]);
      }
      if ((lane & 15) == 0) {
        *reinterpret_cast<f32x4*>(&sumP[wv][crow0]) = (f32x4){s4[0], s4[1], s4[2], s4[3]};
        *reinterpret_cast<f32x4*>(&sqP[wv][crow0])  = (f32x4){q4[0], q4[1], q4[2], q4[3]};
      }
    }
    __syncthreads();                                   // B3

    // ---- cand LN + tanh + h update ----
    {
      int sg = lane >> 4, rr = lane & 15;
      float S = sumP[2 * sg][rr] + sumP[2 * sg + 1][rr];
      float Q = sqP[2 * sg][rr] + sqP[2 * sg + 1][rr];
      S += __shfl_xor(S, 16, 64); Q += __shfl_xor(Q, 16, 64);
      S += __shfl_xor(S, 32, 64); Q += __shfl_xor(Q, 32, 64);
      float mn = S * (1.f / 256.f);
      float rs = __builtin_amdgcn_rsqf(Q * (1.f / 256.f) - mn * mn + EPS_);
      if (lane < 16) mnrs[lane] = make_float2(mn, rs);
    }
    unsigned short* hrow = h0o ? (h0o + (size_t)(bt * TC + tt) * 4096) : (unsigned short*)nullptr;
#pragma unroll
    for (int g = 0; g < 4; ++g) {
      float2 mr = mnrs[crow0 + g];
      float n0 = tanh_(fmaf((vc0[g] - mr.x) * mr.y, cw0, cb0));
      float n1 = tanh_(fmaf((vc1[g] - mr.x) * mr.y, cw1, cb1));
      float h0n = fmaf(zf[0][g], n0 - hm[0][g], hm[0][g]);
      float h1n = fmaf(zf[1][g], n1 - hm[1][g], hm[1][g]);
      hm[0][g] = h0n; hm[1][g] = h1n;
      unsigned short hb0 = f2bf(h0n), hb1 = f2bf(h1n);
      h_s[crow0 + g][colr0] = hb0;
      h_s[crow0 + g][colr1] = hb1;
      if (hrow) {
        hrow[(size_t)(crow0 + g) * 256 + colr0] = hb0;
        hrow[(size_t)(crow0 + g) * 256 + colr1] = hb1;
      }
    }
    __syncthreads();                                   // B4
  }

#pragma unroll
  for (int g = 0; g < 4; ++g) {
    hstate[(size_t)(b0 + crow0 + g) * 256 + colr0] = hm[0][g];
    hstate[(size_t)(b0 + crow0 + g) * 256 + colr1] = hm[1][g];
  }
}

// ------------------------------- FC head -------------------------------------
__launch_bounds__(256)
__global__ void head_k(const float* __restrict__ h1, const float* __restrict__ fcW,
                       const float* __restrict__ fcb, float* __restrict__ out) {
  __shared__ float hs[16][256];
  const int tid = threadIdx.x, b0 = blockIdx.x * 16;
  for (int i = tid; i < 16 * 64; i += 256) {
    int r = i >> 6, c4 = (i & 63) * 4;
    *reinterpret_cast<float4*>(&hs[r][c4]) =
        *reinterpret_cast<const float4*>(&h1[(size_t)(b0 + r) * 256 + c4]);
  }
  __syncthreads();
  int r = tid >> 4, o = (tid & 15) * 4;
  float a0 = fcb[o], a1 = fcb[o + 1], a2 = fcb[o + 2], a3 = fcb[o + 3];
  for (int k = 0; k < 256; ++k) {
    float h = hs[r][k];
    a0 = fmaf(h, fcW[(size_t)(o + 0) * 256 + k], a0);
    a1 = fmaf(h, fcW[(size_t)(o + 1) * 256 + k], a1);
    a2 = fmaf(h, fcW[(size_t)(o + 2) * 256 + k], a2);
    a3 = fmaf(h, fcW[(size_t)(o + 3) * 256 + k], a3);
  }
  float4 ov = {a0, a1, a2, a3};
  *reinterpret_cast<float4*>(&out[(size_t)(b0 + r) * 64 + o]) = ov;
}

// --------------------------------- host --------------------------------------
extern "C" void kernel_launch(void* const* d_in, const int* in_sizes, int n_in,
                              void* d_out, int out_size, void* d_ws, size_t ws_size,
                              hipStream_t stream) {
  (void)in_sizes; (void)n_in; (void)out_size;
  const float* x    = (const float*)d_in[0];
  const float* Wg0  = (const float*)d_in[1];
  const float* bg0  = (const float*)d_in[2];
  const float* gnw0 = (const float*)d_in[3];
  const float* gnb0 = (const float*)d_in[4];
  const float* Wc0  = (const float*)d_in[5];
  const float* bc0  = (const float*)d_in[6];
  const float* cnw0 = (const float*)d_in[7];
  const float* cnb0 = (const float*)d_in[8];
  const float* Wg1  = (const float*)d_in[9];
  const float* bg1  = (const float*)d_in[10];
  const float* gnw1 = (const float*)d_in[11];
  const float* gnb1 = (const float*)d_in[12];
  const float* Wc1  = (const float*)d_in[13];
  const float* bc1  = (const float*)d_in[14];
  const float* cnw1 = (const float*)d_in[15];
  const float* cnb1 = (const float*)d_in[16];
  const float* fcW  = (const float*)d_in[17];
  const float* fcb  = (const float*)d_in[18];

  float* hst0 = (float*)d_ws;                 // 512*256 fp32
  float* hst1 = hst0 + 131072;
  float* b768_0 = hst1 + 131072;
  float* b768_1 = b768_0 + 768;
  unsigned short* g0h = (unsigned short*)(b768_1 + 768);
  unsigned short* c0h = g0h + 131072;
  unsigned short* g1h = c0h + 65536;
  unsigned short* c1h = g1h + 131072;
  unsigned short* wx0 = c1h + 65536;
  unsigned short* wx1 = wx0 + 49152;
  unsigned short* dynbase = wx1 + 196608;

  const size_t fixed_bytes = (size_t)((char*)dynbase - (char*)d_ws);
  int TC = 64;
  while (TC > 8) {
    size_t need = fixed_bytes + (size_t)TC * (262144 + 2 * 786432);
    if (need <= ws_size) break;
    TC >>= 1;
  }
  const int NC = T_ / TC;

  unsigned short* P0c = dynbase;
  unsigned short* P1c = P0c + (size_t)TC * 393216;
  unsigned short* h0c = P1c + (size_t)TC * 393216;

  prep_frag<<<512, 256, 0, stream>>>(Wg0, g0h, 512, 320, 64);
  prep_frag<<<256, 256, 0, stream>>>(Wc0, c0h, 256, 320, 64);
  prep_frag<<<512, 256, 0, stream>>>(Wg1, g1h, 512, 512, 256);
  prep_frag<<<256, 256, 0, stream>>>(Wc1, c1h, 256, 512, 256);
  prep_wx<<<192, 256, 0, stream>>>(Wg0, Wc0, wx0, 64, 320, 320);
  prep_wx<<<768, 256, 0, stream>>>(Wg1, Wc1, wx1, 256, 512, 512);
  bias_cat<<<3, 256, 0, stream>>>(bg0, bc0, b768_0);
  bias_cat<<<3, 256, 0, stream>>>(bg1, bc1, b768_1);

  dim3 pgrid(4 * TC, 6);

  // A(0); B(0); C(0); A(1)
  precomp<64, true><<<pgrid, 256, 0, stream>>>(x, wx0, b768_0, P0c, TC, 0);
  gru_fused<<<32, 512, 0, stream>>>(
      g0h, c0h, P0c, gnw0, gnb0, cnw0, cnb0, hst0, h0c,
      g1h, c1h, P1c, gnw1, gnb1, cnw1, cnb1, hst1,
      1, 0, 1, 0, TC);
  precomp<256, false><<<pgrid, 256, 0, stream>>>(h0c, wx1, b768_1, P1c, TC, 0);
  if (NC > 1)
    precomp<64, true><<<pgrid, 256, 0, stream>>>(x, wx0, b768_0, P0c, TC, TC);

  // pipeline: E(c) = B(c+1) || D(c)
  for (int c = 0; c < NC; ++c) {
    int bAct = (c + 1 < NC) ? 1 : 0;
    gru_fused<<<64, 512, 0, stream>>>(
        g0h, c0h, P0c, gnw0, gnb0, cnw0, cnb0, hst0, h0c,
        g1h, c1h, P1c, gnw1, gnb1, cnw1, cnb1, hst1,
        bAct, 1, 0, (c == 0) ? 1 : 0, TC);
    if (c + 1 < NC)
      precomp<256, false><<<pgrid, 256, 0, stream>>>(h0c, wx1, b768_1, P1c, TC, 0);
    if (c + 2 < NC)
      precomp<64, true><<<pgrid, 256, 0, stream>>>(x, wx0, b768_0, P0c, TC, (c + 2) * TC);
  }

  head_k<<<32, 256, 0, stream>>>(hst1, fcW, fcb, (float*)d_out);
}

// Round 7
// 2631.815 us; speedup vs baseline: 3.8206x; 1.0381x over previous
//
#include <hip/hip_runtime.h>

// ---------------------------------------------------------------------------
// MultiLayerNormGRU on MI355X (gfx950) — round 7.
// One "mega" dispatch per T-chunk with block-role partition:
//   blocks   0- 31 : layer-0 recurrence, chunk k      (R6 inner + prefetch)
//   blocks  32- 63 : layer-1 recurrence, chunk k-2
//   blocks  64-159 : precomp A -> P0 chunk k+1 (x @ Wx0, K=64)
//   blocks 160-255 : precomp C -> P1 chunk k-1 (h0 @ Wx1, K=256)
// All cross-role deps span >=1 dispatch; P0/P1/h0 ping-pong by parity.
// In-step: P prefetch one step ahead; LN stats broadcast via shfl (no LDS
// round trip); gate weights AGPR-pinned; cand weights in LDS.
// ---------------------------------------------------------------------------

#define B_   512
#define T_   512
#define DIN  64
#define H_   256
#define OUT_ 64
#define EPS_ 1e-5f

typedef __attribute__((ext_vector_type(8))) short bf16x8;
typedef __attribute__((ext_vector_type(4))) float f32x4;

__device__ __forceinline__ unsigned short f2bf(float f) {
  unsigned int u = __float_as_uint(f);
  u += 0x7fffu + ((u >> 16) & 1u);          // RNE f32 -> bf16
  return (unsigned short)(u >> 16);
}
__device__ __forceinline__ float bfh(unsigned short u) {
  return __uint_as_float(((unsigned int)u) << 16);
}
__device__ __forceinline__ float sigm_(float x) {
  return __builtin_amdgcn_rcpf(1.f + __expf(-x));
}
__device__ __forceinline__ float tanh_(float x) {
  return 1.f - 2.f * __builtin_amdgcn_rcpf(__expf(2.f * x) + 1.f);
}
template<int C>
__device__ __forceinline__ float dpp_add(float v) {
  int r = __builtin_amdgcn_update_dpp(0, __float_as_int(v), C, 0xF, 0xF, false);
  return v + __int_as_float(r);
}
__device__ __forceinline__ float red16(float v) {  // sum over 16-lane row
  v = dpp_add<0x121>(v);
  v = dpp_add<0x122>(v);
  v = dpp_add<0x124>(v);
  v = dpp_add<0x128>(v);
  return v;
}

#define PIN8A(a) asm volatile("" : "+a"(a[0]), "+a"(a[1]), "+a"(a[2]), "+a"(a[3]), \
                                   "+a"(a[4]), "+a"(a[5]), "+a"(a[6]), "+a"(a[7]))

// ------------------------- prep kernels --------------------------------------
__global__ void prep_frag(const float* __restrict__ w, unsigned short* __restrict__ dst,
                          int N, int Ksrc, int koff) {
  int gid = blockIdx.x * 256 + threadIdx.x;
  if (gid >= N * 256) return;
  int n = gid >> 8, k = gid & 255;
  int idx = (((n >> 4) * 8 + (k >> 5)) * 64 + ((n & 15) + 16 * ((k >> 3) & 3))) * 8 + (k & 7);
  dst[idx] = f2bf(w[(size_t)n * Ksrc + koff + k]);
}

__global__ void prep_wx(const float* __restrict__ wg, const float* __restrict__ wc,
                        unsigned short* __restrict__ dst, int KX, int Kg, int Kc) {
  int gid = blockIdx.x * 256 + threadIdx.x;
  if (gid >= 768 * KX) return;
  int n = gid / KX, k = gid - n * KX;
  float v = (n < 512) ? wg[(size_t)n * Kg + k] : wc[(size_t)(n - 512) * Kc + k];
  dst[gid] = f2bf(v);
}

__global__ void bias_cat(const float* __restrict__ bg, const float* __restrict__ bc,
                         float* __restrict__ dst) {
  int i = blockIdx.x * 256 + threadIdx.x;
  if (i < 768) dst[i] = (i < 512) ? bg[i] : bc[i - 512];
}

// ------------------------- precomp tile (256-thread team) --------------------
__device__ __forceinline__ void precomp_tile(
    const void* __restrict__ Asrc, const unsigned short* __restrict__ wx,
    const float* __restrict__ bias, unsigned short* __restrict__ Pc,
    int TC, int t0, int KX, int AFP32,
    int mi, int nb, unsigned short* A_s, unsigned short* B_s, int t256)
{
  const int lane = t256 & 63, wv = t256 >> 6;     // wv 0..3
  const int m0 = mi * 128;
  const int bt = m0 / (TC * 16);
  const int tt0 = (m0 - bt * TC * 16) >> 4;
  const int mq = wv >> 1, nq = wv & 1;
  const int crow0 = (lane >> 4) * 4;

  f32x4 acc[4][4];
#pragma unroll
  for (int i = 0; i < 4; ++i)
#pragma unroll
    for (int j = 0; j < 4; ++j) acc[i][j] = (f32x4){0, 0, 0, 0};

  for (int kb = 0; kb < (KX >> 6); ++kb) {
    __syncthreads();
#pragma unroll
    for (int it = 0; it < 4; ++it) {
      int s = t256 + it * 256;
      int rg = s >> 3, k8 = s & 7;
      int mt = rg >> 4, r15 = rg & 15;
      int dl = r15 + 16 * (k8 & 3), kc = k8 >> 2;
      if (AFP32) {
        const float* xp = (const float*)Asrc +
            (((size_t)(bt * 16 + r15)) * T_ + (t0 + tt0 + mt)) * DIN + kb * 64 + k8 * 8;
        float4 u0 = *(const float4*)xp, u1 = *(const float4*)(xp + 4);
        unsigned short tmp[8];
        tmp[0] = f2bf(u0.x); tmp[1] = f2bf(u0.y); tmp[2] = f2bf(u0.z); tmp[3] = f2bf(u0.w);
        tmp[4] = f2bf(u1.x); tmp[5] = f2bf(u1.y); tmp[6] = f2bf(u1.z); tmp[7] = f2bf(u1.w);
        *reinterpret_cast<bf16x8*>(&A_s[((mt * 2 + kc) * 64 + dl) * 8]) =
            *reinterpret_cast<bf16x8*>(tmp);
      } else {
        const unsigned short* ap = (const unsigned short*)Asrc +
            ((size_t)(m0 + rg)) * KX + kb * 64 + k8 * 8;
        *reinterpret_cast<bf16x8*>(&A_s[((mt * 2 + kc) * 64 + dl) * 8]) =
            *reinterpret_cast<const bf16x8*>(ap);
      }
      const unsigned short* bp = wx + ((size_t)(nb + rg)) * KX + kb * 64 + k8 * 8;
      *reinterpret_cast<bf16x8*>(&B_s[((mt * 2 + kc) * 64 + dl) * 8]) =
          *reinterpret_cast<const bf16x8*>(bp);
    }
    __syncthreads();
#pragma unroll
    for (int kc = 0; kc < 2; ++kc) {
      bf16x8 av[4], bv[4];
#pragma unroll
      for (int i = 0; i < 4; ++i) {
        av[i] = *reinterpret_cast<const bf16x8*>(&A_s[(((mq * 4 + i) * 2 + kc) * 64 + lane) * 8]);
        bv[i] = *reinterpret_cast<const bf16x8*>(&B_s[(((nq * 4 + i) * 2 + kc) * 64 + lane) * 8]);
      }
#pragma unroll
      for (int i = 0; i < 4; ++i)
#pragma unroll
        for (int j = 0; j < 4; ++j)
          acc[i][j] = __builtin_amdgcn_mfma_f32_16x16x32_bf16(av[i], bv[j], acc[i][j], 0, 0, 0);
    }
  }
  float bb[4];
#pragma unroll
  for (int j = 0; j < 4; ++j) bb[j] = bias[nb + nq * 64 + j * 16 + (lane & 15)];
#pragma unroll
  for (int i = 0; i < 4; ++i) {
    int tt = tt0 + mq * 4 + i;
#pragma unroll
    for (int j = 0; j < 4; ++j) {
      int n = nb + nq * 64 + j * 16 + (lane & 15);
      ushort4 o;
      o.x = f2bf(acc[i][j][0] + bb[j]); o.y = f2bf(acc[i][j][1] + bb[j]);
      o.z = f2bf(acc[i][j][2] + bb[j]); o.w = f2bf(acc[i][j][3] + bb[j]);
      *reinterpret_cast<ushort4*>(&Pc[((size_t)(bt * TC + tt) * 768 + n) * 16 + crow0]) = o;
    }
  }
}

// standalone wrapper for the prologue A(0)
__launch_bounds__(256)
__global__ void precomp_std(const void* __restrict__ Asrc,
                            const unsigned short* __restrict__ wx,
                            const float* __restrict__ bias,
                            unsigned short* __restrict__ Pc,
                            int TC, int t0, int KX, int AFP32) {
  __shared__ __align__(16) unsigned short A_s[8192];
  __shared__ __align__(16) unsigned short B_s[8192];
  precomp_tile(Asrc, wx, bias, Pc, TC, t0, KX, AFP32,
               blockIdx.x, blockIdx.y * 128, A_s, B_s, threadIdx.x);
}

// ------------------------- recurrent body (8 waves) --------------------------
__device__ __forceinline__ void gru_body(
    unsigned char* smem, int bt,
    const unsigned short* __restrict__ gfrag,
    const unsigned short* __restrict__ cfrag,
    const unsigned short* __restrict__ Pc,
    const float* __restrict__ gnw, const float* __restrict__ gnb,
    const float* __restrict__ cnw, const float* __restrict__ cnb,
    float* __restrict__ hstate, unsigned short* __restrict__ h0out,
    int TC, int first)
{
  unsigned short* wc_s = (unsigned short*)smem;                          // 128 KB
  unsigned short (*h_s)[264]  = (unsigned short(*)[264])(smem + 131072); // 8448 B
  unsigned short (*rh_s)[264] = (unsigned short(*)[264])(smem + 139520); // 8448 B
  float (*sumP)[20] = (float(*)[20])(smem + 147968);                     // 640 B
  float (*sqP)[20]  = (float(*)[20])(smem + 148608);                     // 640 B

  const int tid = threadIdx.x, lane = tid & 63, wv = tid >> 6;  // wv 0..7
  const int b0 = bt * 16;
  const int arow = lane & 15, koff = (lane >> 4) * 8, crow0 = (lane >> 4) * 4;
  const int colr0 = 32 * wv + (lane & 15), colr1 = colr0 + 16;
  const int nt0 = 2 * wv, nt1 = 2 * wv + 1, nt2 = 16 + 2 * wv, nt3 = 17 + 2 * wv;

  // cand weights -> LDS (one-time)
  for (int i = tid; i < 8192; i += 512)
    *reinterpret_cast<bf16x8*>(&wc_s[i * 8]) = *reinterpret_cast<const bf16x8*>(&cfrag[i * 8]);

  // gate weights -> AGPR (128 regs), pinned each iteration
  bf16x8 wgr0[8], wgr1[8], wgr2[8], wgr3[8];
#pragma unroll
  for (int kc = 0; kc < 8; ++kc) {
    wgr0[kc] = *reinterpret_cast<const bf16x8*>(&gfrag[((nt0 * 8 + kc) * 64 + lane) * 8]);
    wgr1[kc] = *reinterpret_cast<const bf16x8*>(&gfrag[((nt1 * 8 + kc) * 64 + lane) * 8]);
    wgr2[kc] = *reinterpret_cast<const bf16x8*>(&gfrag[((nt2 * 8 + kc) * 64 + lane) * 8]);
    wgr3[kc] = *reinterpret_cast<const bf16x8*>(&gfrag[((nt3 * 8 + kc) * 64 + lane) * 8]);
  }

  const float gw_r0 = gnw[colr0], gb_r0 = gnb[colr0];
  const float gw_r1 = gnw[colr1], gb_r1 = gnb[colr1];
  const float gw_z0 = gnw[256 + colr0], gb_z0 = gnb[256 + colr0];
  const float gw_z1 = gnw[256 + colr1], gb_z1 = gnb[256 + colr1];
  const float cw0 = cnw[colr0], cb0 = cnb[colr0];
  const float cw1 = cnw[colr1], cb1 = cnb[colr1];

  float hm[2][4];
  if (first) {
#pragma unroll
    for (int g = 0; g < 4; ++g) { hm[0][g] = 0.f; hm[1][g] = 0.f; }
    for (int i = tid; i < 16 * 264; i += 512) (&h_s[0][0])[i] = 0;
  } else {
#pragma unroll
    for (int g = 0; g < 4; ++g) {
      hm[0][g] = hstate[(size_t)(b0 + crow0 + g) * 256 + colr0];
      hm[1][g] = hstate[(size_t)(b0 + crow0 + g) * 256 + colr1];
    }
    int r = tid >> 5, c8 = (tid & 31) * 8;
    float4 v0 = *reinterpret_cast<const float4*>(&hstate[(size_t)(b0 + r) * 256 + c8]);
    float4 v1 = *reinterpret_cast<const float4*>(&hstate[(size_t)(b0 + r) * 256 + c8 + 4]);
    ushort4 o0, o1;
    o0.x = f2bf(v0.x); o0.y = f2bf(v0.y); o0.z = f2bf(v0.z); o0.w = f2bf(v0.w);
    o1.x = f2bf(v1.x); o1.y = f2bf(v1.y); o1.z = f2bf(v1.z); o1.w = f2bf(v1.w);
    *reinterpret_cast<ushort4*>(&h_s[r][c8]) = o0;
    *reinterpret_cast<ushort4*>(&h_s[r][c8 + 4]) = o1;
  }
  __syncthreads();

  const unsigned short* Pr = Pc + ((size_t)bt * TC * 768 + colr0) * 16;
  // prefetch step 0
  ushort4 npr0 = *reinterpret_cast<const ushort4*>(Pr + crow0);
  ushort4 npr1 = *reinterpret_cast<const ushort4*>(Pr + 256 + crow0);
  ushort4 npz0 = *reinterpret_cast<const ushort4*>(Pr + 4096 + crow0);
  ushort4 npz1 = *reinterpret_cast<const ushort4*>(Pr + 4352 + crow0);
  ushort4 npn0 = *reinterpret_cast<const ushort4*>(Pr + 8192 + crow0);
  ushort4 npn1 = *reinterpret_cast<const ushort4*>(Pr + 8448 + crow0);

  for (int tt = 0; tt < TC; ++tt) {
    PIN8A(wgr0); PIN8A(wgr1); PIN8A(wgr2); PIN8A(wgr3);

    ushort4 pr0 = npr0, pr1 = npr1, pz0 = npz0, pz1 = npz1, pn0 = npn0, pn1 = npn1;
    if (tt + 1 < TC) {   // prefetch next step's P (hidden under this step)
      Pr += 12288;
      npr0 = *reinterpret_cast<const ushort4*>(Pr + crow0);
      npr1 = *reinterpret_cast<const ushort4*>(Pr + 256 + crow0);
      npz0 = *reinterpret_cast<const ushort4*>(Pr + 4096 + crow0);
      npz1 = *reinterpret_cast<const ushort4*>(Pr + 4352 + crow0);
      npn0 = *reinterpret_cast<const ushort4*>(Pr + 8192 + crow0);
      npn1 = *reinterpret_cast<const ushort4*>(Pr + 8448 + crow0);
    }

    // ---- gates MFMA (AGPR weights) ----
    f32x4 a0 = {0, 0, 0, 0}, a1 = {0, 0, 0, 0}, a2 = {0, 0, 0, 0}, a3 = {0, 0, 0, 0};
#pragma unroll
    for (int kc = 0; kc < 8; ++kc) {
      bf16x8 av = *reinterpret_cast<const bf16x8*>(&h_s[arow][kc * 32 + koff]);
      a0 = __builtin_amdgcn_mfma_f32_16x16x32_bf16(av, wgr0[kc], a0, 0, 0, 0);
      a1 = __builtin_amdgcn_mfma_f32_16x16x32_bf16(av, wgr1[kc], a1, 0, 0, 0);
      a2 = __builtin_amdgcn_mfma_f32_16x16x32_bf16(av, wgr2[kc], a2, 0, 0, 0);
      a3 = __builtin_amdgcn_mfma_f32_16x16x32_bf16(av, wgr3[kc], a3, 0, 0, 0);
    }
    float vr0[4], vr1[4], vz0[4], vz1[4];
    {
      float s4[4], q4[4];
#pragma unroll
      for (int g = 0; g < 4; ++g) {
        vr0[g] = a0[g] + bfh(((const unsigned short*)&pr0)[g]);
        vr1[g] = a1[g] + bfh(((const unsigned short*)&pr1)[g]);
        vz0[g] = a2[g] + bfh(((const unsigned short*)&pz0)[g]);
        vz1[g] = a3[g] + bfh(((const unsigned short*)&pz1)[g]);
        s4[g] = red16(vr0[g] + vr1[g] + vz0[g] + vz1[g]);
        q4[g] = red16(vr0[g] * vr0[g] + vr1[g] * vr1[g] + vz0[g] * vz0[g] + vz1[g] * vz1[g]);
      }
      if ((lane & 15) == 0) {
        *reinterpret_cast<f32x4*>(&sumP[wv][crow0]) = (f32x4){s4[0], s4[1], s4[2], s4[3]};
        *reinterpret_cast<f32x4*>(&sqP[wv][crow0])  = (f32x4){q4[0], q4[1], q4[2], q4[3]};
      }
    }
    __syncthreads();                                   // B1

    // ---- gate LN stats (shfl broadcast) + apply ----
    float zf[2][4];
    {
      int sg = lane >> 4, rr = lane & 15;
      float S = sumP[2 * sg][rr] + sumP[2 * sg + 1][rr];
      float Q = sqP[2 * sg][rr] + sqP[2 * sg + 1][rr];
      S += __shfl_xor(S, 16, 64); Q += __shfl_xor(Q, 16, 64);
      S += __shfl_xor(S, 32, 64); Q += __shfl_xor(Q, 32, 64);
      float mn = S * (1.f / 512.f);
      float rs = __builtin_amdgcn_rsqf(Q * (1.f / 512.f) - mn * mn + EPS_);
#pragma unroll
      for (int g = 0; g < 4; ++g) {
        float m_ = __shfl(mn, crow0 + g, 64);
        float r_ = __shfl(rs, crow0 + g, 64);
        float rv0 = sigm_(fmaf((vr0[g] - m_) * r_, gw_r0, gb_r0));
        float rv1 = sigm_(fmaf((vr1[g] - m_) * r_, gw_r1, gb_r1));
        zf[0][g]  = sigm_(fmaf((vz0[g] - m_) * r_, gw_z0, gb_z0));
        zf[1][g]  = sigm_(fmaf((vz1[g] - m_) * r_, gw_z1, gb_z1));
        rh_s[crow0 + g][colr0] = f2bf(rv0 * hm[0][g]);
        rh_s[crow0 + g][colr1] = f2bf(rv1 * hm[1][g]);
      }
    }
    __syncthreads();                                   // B2

    // ---- cand MFMA (LDS weights) ----
    f32x4 c0a = {0, 0, 0, 0}, c1a = {0, 0, 0, 0};
#pragma unroll
    for (int kc = 0; kc < 8; ++kc) {
      bf16x8 av = *reinterpret_cast<const bf16x8*>(&rh_s[arow][kc * 32 + koff]);
      bf16x8 b0v = *reinterpret_cast<const bf16x8*>(&wc_s[((nt0 * 8 + kc) * 64 + lane) * 8]);
      bf16x8 b1v = *reinterpret_cast<const bf16x8*>(&wc_s[((nt1 * 8 + kc) * 64 + lane) * 8]);
      c0a = __builtin_amdgcn_mfma_f32_16x16x32_bf16(av, b0v, c0a, 0, 0, 0);
      c1a = __builtin_amdgcn_mfma_f32_16x16x32_bf16(av, b1v, c1a, 0, 0, 0);
    }
    float vc0[4], vc1[4];
    {
      float s4[4], q4[4];
#pragma unroll
      for (int g = 0; g < 4; ++g) {
        vc0[g] = c0a[g] + bfh(((const unsigned short*)&pn0)[g]);
        vc1[g] = c1a[g] + bfh(((const unsigned short*)&pn1)[g]);
        s4[g] = red16(vc0[g] + vc1[g]);
        q4[g] = red16(vc0[g] * vc0[g] + vc1[g] * vc1[g]);
      }
      if ((lane & 15) == 0) {
        *reinterpret_cast<f32x4*>(&sumP[wv][crow0]) = (f32x4){s4[0], s4[1], s4[2], s4[3]};
        *reinterpret_cast<f32x4*>(&sqP[wv][crow0])  = (f32x4){q4[0], q4[1], q4[2], q4[3]};
      }
    }
    __syncthreads();                                   // B3

    // ---- cand LN (shfl broadcast) + tanh + h update ----
    {
      int sg = lane >> 4, rr = lane & 15;
      float S = sumP[2 * sg][rr] + sumP[2 * sg + 1][rr];
      float Q = sqP[2 * sg][rr] + sqP[2 * sg + 1][rr];
      S += __shfl_xor(S, 16, 64); Q += __shfl_xor(Q, 16, 64);
      S += __shfl_xor(S, 32, 64); Q += __shfl_xor(Q, 32, 64);
      float mn = S * (1.f / 256.f);
      float rs = __builtin_amdgcn_rsqf(Q * (1.f / 256.f) - mn * mn + EPS_);
      unsigned short* hrow = h0out ? (h0out + (size_t)(bt * TC + tt) * 4096) : (unsigned short*)nullptr;
#pragma unroll
      for (int g = 0; g < 4; ++g) {
        float m_ = __shfl(mn, crow0 + g, 64);
        float r_ = __shfl(rs, crow0 + g, 64);
        float n0 = tanh_(fmaf((vc0[g] - m_) * r_, cw0, cb0));
        float n1 = tanh_(fmaf((vc1[g] - m_) * r_, cw1, cb1));
        float h0n = fmaf(zf[0][g], n0 - hm[0][g], hm[0][g]);
        float h1n = fmaf(zf[1][g], n1 - hm[1][g], hm[1][g]);
        hm[0][g] = h0n; hm[1][g] = h1n;
        unsigned short hb0 = f2bf(h0n), hb1 = f2bf(h1n);
        h_s[crow0 + g][colr0] = hb0;
        h_s[crow0 + g][colr1] = hb1;
        if (hrow) {
          hrow[(size_t)(crow0 + g) * 256 + colr0] = hb0;
          hrow[(size_t)(crow0 + g) * 256 + colr1] = hb1;
        }
      }
    }
    __syncthreads();                                   // B4
  }

#pragma unroll
  for (int g = 0; g < 4; ++g) {
    hstate[(size_t)(b0 + crow0 + g) * 256 + colr0] = hm[0][g];
    hstate[(size_t)(b0 + crow0 + g) * 256 + colr1] = hm[1][g];
  }
}

// ------------------------------- mega kernel ---------------------------------
__launch_bounds__(512, 2)
__global__ void mega(
    const float* __restrict__ x,
    const unsigned short* __restrict__ g0h, const unsigned short* __restrict__ c0h,
    const unsigned short* __restrict__ g1h, const unsigned short* __restrict__ c1h,
    const unsigned short* __restrict__ wx0, const unsigned short* __restrict__ wx1,
    const float* __restrict__ b768_0, const float* __restrict__ b768_1,
    const float* __restrict__ gnw0, const float* __restrict__ gnb0,
    const float* __restrict__ cnw0, const float* __restrict__ cnb0,
    const float* __restrict__ gnw1, const float* __restrict__ gnb1,
    const float* __restrict__ cnw1, const float* __restrict__ cnb1,
    float* __restrict__ hst0, float* __restrict__ hst1,
    unsigned short* __restrict__ P0a, unsigned short* __restrict__ P0b,
    unsigned short* __restrict__ P1a, unsigned short* __restrict__ P1b,
    unsigned short* __restrict__ h0a, unsigned short* __restrict__ h0b,
    int k, int TC, int NC)
{
  __shared__ __align__(16) unsigned char smem[149504];
  const int bid = blockIdx.x;

  if (bid < 32) {                       // ---- B: layer-0 chunk k ----
    if (k >= NC) return;
    unsigned short* P0 = (k & 1) ? P0b : P0a;
    unsigned short* h0 = (k & 1) ? h0b : h0a;
    gru_body(smem, bid, g0h, c0h, P0, gnw0, gnb0, cnw0, cnb0, hst0, h0, TC, k == 0);
  } else if (bid < 64) {                // ---- D: layer-1 chunk k-2 ----
    int kD = k - 2;
    if (kD < 0 || kD >= NC) return;
    unsigned short* P1 = (kD & 1) ? P1b : P1a;
    gru_body(smem, bid - 32, g1h, c1h, P1, gnw1, gnb1, cnw1, cnb1, hst1,
             (unsigned short*)nullptr, TC, kD == 0);
  } else if (bid < 160) {               // ---- A: precomp P0 chunk k+1 ----
    int kA = k + 1;
    if (kA >= NC) return;
    unsigned short* P0 = (kA & 1) ? P0b : P0a;
    int team = (bid - 64) * 2 + (threadIdx.x >> 8);
    int t256 = threadIdx.x & 255;
    unsigned short* A_s = (unsigned short*)(smem + (threadIdx.x >> 8) * 32768);
    unsigned short* B_s = A_s + 8192;
    int ntile = 24 * TC;                // (4*TC m-tiles) x 6 n-tiles
    for (int i = team; i < ntile; i += 192) {
      int mi = i % (4 * TC), ni = i / (4 * TC);
      precomp_tile(x, wx0, b768_0, P0, TC, kA * TC, 64, 1, mi, ni * 128, A_s, B_s, t256);
    }
  } else {                              // ---- C: precomp P1 chunk k-1 ----
    int kC = k - 1;
    if (kC < 0 || kC >= NC) return;
    const unsigned short* h0 = (kC & 1) ? h0b : h0a;
    unsigned short* P1 = (kC & 1) ? P1b : P1a;
    int team = (bid - 160) * 2 + (threadIdx.x >> 8);
    int t256 = threadIdx.x & 255;
    unsigned short* A_s = (unsigned short*)(smem + (threadIdx.x >> 8) * 32768);
    unsigned short* B_s = A_s + 8192;
    int ntile = 24 * TC;
    for (int i = team; i < ntile; i += 192) {
      int mi = i % (4 * TC), ni = i / (4 * TC);
      precomp_tile(h0, wx1, b768_1, P1, TC, 0, 256, 0, mi, ni * 128, A_s, B_s, t256);
    }
  }
}

// ------------------------------- FC head -------------------------------------
__launch_bounds__(256)
__global__ void head_k(const float* __restrict__ h1, const float* __restrict__ fcW,
                       const float* __restrict__ fcb, float* __restrict__ out) {
  __shared__ float hs[16][256];
  const int tid = threadIdx.x, b0 = blockIdx.x * 16;
  for (int i = tid; i < 16 * 64; i += 256) {
    int r = i >> 6, c4 = (i & 63) * 4;
    *reinterpret_cast<float4*>(&hs[r][c4]) =
        *reinterpret_cast<const float4*>(&h1[(size_t)(b0 + r) * 256 + c4]);
  }
  __syncthreads();
  int r = tid >> 4, o = (tid & 15) * 4;
  float a0 = fcb[o], a1 = fcb[o + 1], a2 = fcb[o + 2], a3 = fcb[o + 3];
  for (int k = 0; k < 256; ++k) {
    float h = hs[r][k];
    a0 = fmaf(h, fcW[(size_t)(o + 0) * 256 + k], a0);
    a1 = fmaf(h, fcW[(size_t)(o + 1) * 256 + k], a1);
    a2 = fmaf(h, fcW[(size_t)(o + 2) * 256 + k], a2);
    a3 = fmaf(h, fcW[(size_t)(o + 3) * 256 + k], a3);
  }
  float4 ov = {a0, a1, a2, a3};
  *reinterpret_cast<float4*>(&out[(size_t)(b0 + r) * 64 + o]) = ov;
}

// --------------------------------- host --------------------------------------
extern "C" void kernel_launch(void* const* d_in, const int* in_sizes, int n_in,
                              void* d_out, int out_size, void* d_ws, size_t ws_size,
                              hipStream_t stream) {
  (void)in_sizes; (void)n_in; (void)out_size;
  const float* x    = (const float*)d_in[0];
  const float* Wg0  = (const float*)d_in[1];
  const float* bg0  = (const float*)d_in[2];
  const float* gnw0 = (const float*)d_in[3];
  const float* gnb0 = (const float*)d_in[4];
  const float* Wc0  = (const float*)d_in[5];
  const float* bc0  = (const float*)d_in[6];
  const float* cnw0 = (const float*)d_in[7];
  const float* cnb0 = (const float*)d_in[8];
  const float* Wg1  = (const float*)d_in[9];
  const float* bg1  = (const float*)d_in[10];
  const float* gnw1 = (const float*)d_in[11];
  const float* gnb1 = (const float*)d_in[12];
  const float* Wc1  = (const float*)d_in[13];
  const float* bc1  = (const float*)d_in[14];
  const float* cnw1 = (const float*)d_in[15];
  const float* cnb1 = (const float*)d_in[16];
  const float* fcW  = (const float*)d_in[17];
  const float* fcb  = (const float*)d_in[18];

  float* hst0 = (float*)d_ws;                 // 512*256 fp32
  float* hst1 = hst0 + 131072;
  float* b768_0 = hst1 + 131072;
  float* b768_1 = b768_0 + 768;
  unsigned short* g0h = (unsigned short*)(b768_1 + 768);
  unsigned short* c0h = g0h + 131072;
  unsigned short* g1h = c0h + 65536;
  unsigned short* c1h = g1h + 131072;
  unsigned short* wx0 = c1h + 65536;
  unsigned short* wx1 = wx0 + 49152;
  unsigned short* dynbase = wx1 + 196608;

  const size_t fixed_bytes = (size_t)((char*)dynbase - (char*)d_ws);
  int TC = 32;
  while (TC > 4) {
    size_t need = fixed_bytes + (size_t)TC * 3670016;  // 2x(P0+P1) + 2x h0
    if (need <= ws_size) break;
    TC >>= 1;
  }
  const int NC = T_ / TC;

  unsigned short* P0a = dynbase;
  unsigned short* P0b = P0a + (size_t)TC * 393216;
  unsigned short* P1a = P0b + (size_t)TC * 393216;
  unsigned short* P1b = P1a + (size_t)TC * 393216;
  unsigned short* h0a = P1b + (size_t)TC * 393216;
  unsigned short* h0b = h0a + (size_t)TC * 131072;

  prep_frag<<<512, 256, 0, stream>>>(Wg0, g0h, 512, 320, 64);
  prep_frag<<<256, 256, 0, stream>>>(Wc0, c0h, 256, 320, 64);
  prep_frag<<<512, 256, 0, stream>>>(Wg1, g1h, 512, 512, 256);
  prep_frag<<<256, 256, 0, stream>>>(Wc1, c1h, 256, 512, 256);
  prep_wx<<<192, 256, 0, stream>>>(Wg0, Wc0, wx0, 64, 320, 320);
  prep_wx<<<768, 256, 0, stream>>>(Wg1, Wc1, wx1, 256, 512, 512);
  bias_cat<<<3, 256, 0, stream>>>(bg0, bc0, b768_0);
  bias_cat<<<3, 256, 0, stream>>>(bg1, bc1, b768_1);

  // prologue: A(0) -> P0a
  precomp_std<<<dim3(4 * TC, 6), 256, 0, stream>>>(x, wx0, b768_0, P0a, TC, 0, 64, 1);

  for (int k = 0; k < NC + 2; ++k) {
    mega<<<256, 512, 0, stream>>>(x, g0h, c0h, g1h, c1h, wx0, wx1, b768_0, b768_1,
        gnw0, gnb0, cnw0, cnb0, gnw1, gnb1, cnw1, cnb1,
        hst0, hst1, P0a, P0b, P1a, P1b, h0a, h0b, k, TC, NC);
  }

  head_k<<<32, 256, 0, stream>>>(hst1, fcW, fcb, (float*)d_out);
}